// Round 6
// baseline (5283.533 us; speedup 1.0000x reference)
//
#include <hip/hip_runtime.h>
#include <math.h>

#define N 4096
#define STEPS 16384
#define WIN 32                 // steps resolved per barrier pair
#define NWIN (STEPS / WIN)
#define MBLK 1024
#define SBS 36      // padded stride (floats) for 32-wide coupling blocks
#define RSTAGE 8    // flip rows staged in worker registers (32+8 VGPR)
#define NW (MBLK - 64)    // 960 worker threads (waves 1..15)
#define XBASE (4 * NW)    // 3840: first 3840 field elements owned 4-per-worker
#define NX (N - XBASE)    // 256 extras owned 1-each by tid 64..319

// Workgroup barrier that does NOT drain vmcnt (LDS-only ordering between phases).
__device__ __forceinline__ void lgkm_barrier() {
  asm volatile("s_waitcnt lgkmcnt(0)\n\ts_barrier" ::: "memory");
}

// ---- prep: thr[t] = atanh(2u-1) in fp64; samemask[t] = window bits with same idx ----
__global__ __launch_bounds__(256) void pre_kernel(const float* __restrict__ u,
                                                  const int* __restrict__ idx,
                                                  double* __restrict__ thr,
                                                  int* __restrict__ samemask) {
  int t = blockIdx.x * 256 + threadIdx.x;
  if (t < STEPS) {
    float r = 2.0f * u[t] - 1.0f;          // exact same fp32 rounding as reference
    double rd = (double)r;
    thr[t] = 0.5 * log((1.0 + rd) / (1.0 - rd));   // r=-1 -> -inf (tie->+1 matches ref)
    int cbase = t & ~(WIN - 1);
    int my = idx[t];
    unsigned int sm = 0u;
    for (int q = 0; q < WIN; ++q)
      if (idx[cbase + q] == my) sm |= (1u << q);   // includes self bit
    samemask[t] = (int)sm;
  }
}

// ---- initial field: I0[row] = sum_k J[row,k]*m0[k] + h[row], fp64 accumulate ----
__global__ __launch_bounds__(256) void init_field_kernel(const float* __restrict__ J,
                                                         const float* __restrict__ h,
                                                         const float* __restrict__ m0,
                                                         double* __restrict__ I) {
  __shared__ double red[256];
  int row = blockIdx.x;
  const float4* Jr = (const float4*)(J + (size_t)row * N);
  const float4* mv = (const float4*)m0;
  double acc = 0.0;
  for (int q = threadIdx.x; q < N / 4; q += 256) {
    float4 a = Jr[q];
    float4 b = mv[q];
    acc += (double)(a.x * b.x) + (double)(a.y * b.y) +
           (double)(a.z * b.z) + (double)(a.w * b.w);
  }
  red[threadIdx.x] = acc;
  __syncthreads();
  for (int s = 128; s > 0; s >>= 1) {
    if (threadIdx.x < s) red[threadIdx.x] += red[threadIdx.x + s];
    __syncthreads();
  }
  if (threadIdx.x == 0) I[row] = red[0] + (double)h[row];
}

// ---- window-resolved Glauber chain, deferred apply: 1 workgroup, 1024 threads ----
// P1(k): wave0 resolves window k flip-driven. Field lags one window (through
//   k-2); xacc (computed last P2 from the SX^T block) supplies window k-1's
//   cross terms; register ST fragments supply in-window couplings. Issues the
//   G(k+1) gather (rows J[idx_{k+1}] x cols [idx_{k+1} | idx_k]) at phase START
//   so its wait lands in P2. Workers are PARKED at the barrier (proven regime).
// P2(k): workers FMA-apply window k-1's flips from REGISTER-staged rows (loaded
//   last P2, landed during P1 -> zero exposure; F>RSTAGE excess via direct
//   loads, early windows only), then stage window k's rows. Wave0 stores G
//   (vmcnt wait overlaps worker FMAs), prefetches ST fragments for k+1, and
//   computes xacc from SX^T (conflict-free LDS reads).
__global__ __launch_bounds__(MBLK) void pbit_kernel(const float* __restrict__ J,
                                                    const float* __restrict__ m0,
                                                    const int* __restrict__ idx,
                                                    const double* __restrict__ thr,
                                                    const int* __restrict__ samemask,
                                                    const double* __restrict__ I0,
                                                    float* __restrict__ out) {
  __shared__ __align__(16) double field_lds[N];        // 32 KB master field
  __shared__ __align__(16) float m_lds[N];             // 16 KB spins
  __shared__ __align__(16) float ST_lds[WIN * SBS];    // ST[r*SBS+c] = J[idx_w[r]][idx_w[c]]
  __shared__ __align__(16) float SXT_lds[WIN * SBS];   // SXT[c*SBS+r] = J[idx_{w}[r]][idx_{w-1}[c]]
  __shared__ __align__(16) int   pubi_lds[2][WIN];     // flip row indices (compacted)
  __shared__ __align__(16) float pubd_lds[2][WIN];     // flip deltas (+/-2)
  __shared__ __align__(16) int   pubs_lds[2][WIN];     // flip window slots
  __shared__ int pubF_lds[2];                          // flip counts

  const int tid = threadIdx.x;

  // field_lds init by launch layout
  {
    const double* ip = I0 + 4 * tid;
    double a = ip[0], b = ip[1], c = ip[2], d = ip[3];
    *(double2*)(field_lds + 4 * tid + 0) = make_double2(a, b);
    *(double2*)(field_lds + 4 * tid + 2) = make_double2(c, d);
  }
  ((float4*)m_lds)[tid] = ((const float4*)m0)[tid];
  if (tid == 0) { pubF_lds[0] = 0; pubF_lds[1] = 0; }

  const int t32 = tid & 31;      // step slot within window (lanes 32-63 duplicate)
  const int jrow = tid >> 1;     // gather row slot (wave0: 0..31)

  // ---- worker field ownership: fp64 registers + LDS write-through ----
  const bool isw = (tid >= 64);
  const int wid = isw ? (tid - 64) : 0;
  const bool isx = isw && (tid < 64 + NX);
  double i0 = 0.0, i1 = 0.0, i2 = 0.0, i3 = 0.0, i4 = 0.0;
  if (isw) {
    const double* ip = I0 + 4 * wid;
    i0 = ip[0]; i1 = ip[1]; i2 = ip[2]; i3 = ip[3];
    if (isx) i4 = I0[XBASE + wid];
  }
  const float* Jb = J + 4 * (size_t)wid;
  const float* Jx = J + XBASE + (size_t)wid;
  float4 rv[RSTAGE];                           // staged flip-row slices
  float rxv[RSTAGE] = {0, 0, 0, 0, 0, 0, 0, 0};

  // ---- wave0 pipeline registers ----
  int mi = 0, ni = 0;
  unsigned int msm = 0u, nsm = 0u;
  double mt = 0.0, nt = 0.0;
  double xacc = 0.0;
  float gv[32];                                // in-flight G block values
  float4 s0, s1, s2, s3, s4, s5, s6, s7;       // ST register row (current window)
  s0 = s1 = s2 = s3 = s4 = s5 = s6 = s7 = make_float4(0.f, 0.f, 0.f, 0.f);

  if (tid < 64) {
    mi = idx[t32];       mt = thr[t32];       msm = (unsigned int)samemask[t32];
    ni = idx[WIN + t32]; nt = thr[WIN + t32]; nsm = (unsigned int)samemask[WIN + t32];
    // synchronous ST(0) gather (SXT not needed for window 0; xacc=0)
    int r0 = __shfl(mi, jrow);
    int half = (tid & 1) * 16;
    const float* Jr = J + (size_t)r0 * N;
#pragma unroll
    for (int q = 0; q < 16; ++q) {
      int c = __shfl(mi, half + q);
      ST_lds[jrow * SBS + half + q] = Jr[c];
    }
  }
  __syncthreads();
  if (tid < 64) {
    const float* sp = &ST_lds[(size_t)t32 * SBS];
    s0 = *(const float4*)(sp + 0);  s1 = *(const float4*)(sp + 4);
    s2 = *(const float4*)(sp + 8);  s3 = *(const float4*)(sp + 12);
    s4 = *(const float4*)(sp + 16); s5 = *(const float4*)(sp + 20);
    s6 = *(const float4*)(sp + 24); s7 = *(const float4*)(sp + 28);
  }

  for (int k = 0; k < NWIN; ++k) {
    const int cur = k & 1;
    const int prv = cur ^ 1;
    // ================= P1: wave0 resolves window k; workers park =================
    if (tid < 64) {
      // issue G(k+1): rows ni; even lanes cols ni (ST), odd lanes cols mi (SXT)
      {
        int grow = __shfl(ni, jrow);
        const float* Jg = J + (size_t)grow * N;
#pragma unroll
        for (int q = 0; q < 32; ++q) {
          int cN = __shfl(ni, q);
          int cM = __shfl(mi, q);
          gv[q] = Jg[(tid & 1) ? cM : cN];
        }
      }
      // step-data loads for window k+2
      int b2 = (k + 2) * WIN; if (b2 >= STEPS) b2 = 0;   // clamp: unused on tail
      int n2i = idx[b2 + t32];
      double n2t = thr[b2 + t32];
      unsigned int n2sm = (unsigned int)samemask[b2 + t32];
      // ---- flip-driven resolve (field through k-2 + xacc covers k-1) ----
      double Ival = field_lds[mi] + xacc;
      float mycur = m_lds[mi];
      float finals = 0.0f, finald = 0.0f;
      int conf = -1;
      bool locked = false;
      while (true) {
        float s = (Ival >= mt) ? 1.0f : -1.0f;   // I >= atanh(r) <=> tanh(I) >= r
        float dl = s - mycur;
        unsigned long long mask = __ballot(dl != 0.0f) & 0xFFFFFFFFull;
        mask &= (~0ull) << (conf + 1);
        if (mask == 0) {
          if (!locked) { finals = s; finald = 0.0f; }
          break;
        }
        int f = (int)__builtin_ctzll(mask);      // wave-uniform
        if (!locked && t32 <= f) { finals = s; finald = dl; locked = true; }
        float dl_f = __int_as_float(__builtin_amdgcn_readlane(__float_as_int(dl), f));
        float s_f  = __int_as_float(__builtin_amdgcn_readlane(__float_as_int(s), f));
        int   i_f  = __builtin_amdgcn_readlane(mi, f);
        float4 sel;                               // f uniform -> scalar branches
        switch (f >> 2) {
          case 0: sel = s0; break; case 1: sel = s1; break;
          case 2: sel = s2; break; case 3: sel = s3; break;
          case 4: sel = s4; break; case 5: sel = s5; break;
          case 6: sel = s6; break; default: sel = s7; break;
        }
        float xcol;
        switch (f & 3) {
          case 0: xcol = sel.x; break; case 1: xcol = sel.y; break;
          case 2: xcol = sel.z; break; default: xcol = sel.w; break;
        }
        Ival += (double)(xcol * dl_f);            // exact product: dl in {-2,2}
        if (mi == i_f) mycur = s_f;               // in-window duplicate index
        conf = f;
      }
      // publish: compacted flip list (rows, deltas, slots) + m updates
      unsigned long long fm = __ballot((tid < WIN) && (finald != 0.0f));
      if (tid < WIN) {
        if (finald != 0.0f) {
          int pos = __popcll(fm & ((1ull << t32) - 1ull));
          pubi_lds[cur][pos] = mi;
          pubd_lds[cur][pos] = finald;
          pubs_lds[cur][pos] = t32;
        }
        bool mlo = (msm & (0xFFFFFFFEu << t32)) == 0u;   // no later same-idx step
        if (mlo) m_lds[mi] = finals;
        if (tid == 0) pubF_lds[cur] = (int)__popcll(fm);
      }
      // rotate step-data pipeline
      mi = ni;  mt = nt;  msm = nsm;
      ni = n2i; nt = n2t; nsm = n2sm;
    }
    lgkm_barrier();
    // ================= P2: apply + staging =================
    if (tid < 64) {
      // store G(k+1): vmcnt wait lands here, overlapping worker FMAs
      if (tid & 1) {
#pragma unroll
        for (int q = 0; q < 32; ++q) SXT_lds[q * SBS + jrow] = gv[q];
      } else {
        float* dst = &ST_lds[jrow * SBS];
#pragma unroll
        for (int q = 0; q < 8; ++q)
          *(float4*)(dst + 4 * q) =
              make_float4(gv[4 * q + 0], gv[4 * q + 1], gv[4 * q + 2], gv[4 * q + 3]);
      }
      // prefetch ST fragments for resolve(k+1) (same-wave DS ordering)
      const float* sp = &ST_lds[(size_t)t32 * SBS];
      s0 = *(const float4*)(sp + 0);  s1 = *(const float4*)(sp + 4);
      s2 = *(const float4*)(sp + 8);  s3 = *(const float4*)(sp + 12);
      s4 = *(const float4*)(sp + 16); s5 = *(const float4*)(sp + 20);
      s6 = *(const float4*)(sp + 24); s7 = *(const float4*)(sp + 28);
      // xacc for resolve(k+1): window k's flips through SXT(k->k+1)
      double xa = 0.0;
      int F = pubF_lds[cur];
#pragma unroll
      for (int t = 0; t < WIN; ++t)
        if (t < F) {
          int st = pubs_lds[cur][t];               // broadcast
          float dlt = pubd_lds[cur][t];            // broadcast
          float v = SXT_lds[st * SBS + t32];       // lanes consecutive: conflict-free
          xa += (double)(v * dlt);
        }
      xacc = xa;
    } else {
      // ---- FMA-apply window k-1's flips ----
      int Fap = pubF_lds[prv];
      if (Fap > 0) {                       // uniform
        float4 d0 = *(const float4*)(pubd_lds[prv] + 0);
        float4 d1 = *(const float4*)(pubd_lds[prv] + 4);
        float dvv[RSTAGE] = {d0.x, d0.y, d0.z, d0.w, d1.x, d1.y, d1.z, d1.w};
        float a0 = 0.f, a1 = 0.f, a2 = 0.f, a3 = 0.f, ax = 0.f;
        // staged rows (loaded last P2, landed during P1: zero exposure)
#pragma unroll
        for (int t = 0; t < RSTAGE; ++t)
          if (t < Fap) {
            a0 += rv[t].x * dvv[t]; a1 += rv[t].y * dvv[t];
            a2 += rv[t].z * dvv[t]; a3 += rv[t].w * dvv[t];
            ax += rxv[t] * dvv[t];
          }
        // excess rows via direct loads (early windows only)
#pragma unroll
        for (int b = RSTAGE; b < WIN; b += 8) {
          if (b < Fap) {                   // uniform
            int4 r1 = *(const int4*)(pubi_lds[prv] + b);
            int4 r2 = *(const int4*)(pubi_lds[prv] + b + 4);
            float4 e1 = *(const float4*)(pubd_lds[prv] + b);
            float4 e2 = *(const float4*)(pubd_lds[prv] + b + 4);
            int rr[8] = {r1.x, r1.y, r1.z, r1.w, r2.x, r2.y, r2.z, r2.w};
            float dd[8] = {e1.x, e1.y, e1.z, e1.w, e2.x, e2.y, e2.z, e2.w};
            float4 tv[8];
            float tx[8] = {0, 0, 0, 0, 0, 0, 0, 0};
#pragma unroll
            for (int t = 0; t < 8; ++t)
              if (b + t < Fap) tv[t] = *(const float4*)(Jb + (size_t)rr[t] * N);
            if (isx) {
#pragma unroll
              for (int t = 0; t < 8; ++t)
                if (b + t < Fap) tx[t] = Jx[(size_t)rr[t] * N];
            }
#pragma unroll
            for (int t = 0; t < 8; ++t)
              if (b + t < Fap) {
                a0 += tv[t].x * dd[t]; a1 += tv[t].y * dd[t];
                a2 += tv[t].z * dd[t]; a3 += tv[t].w * dd[t];
                ax += tx[t] * dd[t];
              }
          }
        }
        i0 += (double)a0; i1 += (double)a1;
        i2 += (double)a2; i3 += (double)a3;
        *(double2*)(field_lds + 4 * wid + 0) = make_double2(i0, i1);
        *(double2*)(field_lds + 4 * wid + 2) = make_double2(i2, i3);
        if (isx) { i4 += (double)ax; field_lds[XBASE + wid] = i4; }
      }
      // ---- stage window k's flip rows (consumed next P2) ----
      int Fs = pubF_lds[cur];
      if (Fs > 0) {                        // uniform
        int4 ra = *(const int4*)(pubi_lds[cur] + 0);
        int4 rb = *(const int4*)(pubi_lds[cur] + 4);
        int rows8[RSTAGE] = {ra.x, ra.y, ra.z, ra.w, rb.x, rb.y, rb.z, rb.w};
#pragma unroll
        for (int t = 0; t < RSTAGE; ++t)
          if (t < Fs) {
            rv[t] = *(const float4*)(Jb + (size_t)rows8[t] * N);
            if (isx) rxv[t] = Jx[(size_t)rows8[t] * N];
          }
      }
    }
    lgkm_barrier();
  }

  __syncthreads();
  ((float4*)out)[tid] = ((const float4*)m_lds)[tid];
}

extern "C" void kernel_launch(void* const* d_in, const int* in_sizes, int n_in,
                              void* d_out, int out_size, void* d_ws, size_t ws_size,
                              hipStream_t stream) {
  const float* J = (const float*)d_in[0];
  const float* h = (const float*)d_in[1];
  const float* m0 = (const float*)d_in[2];
  const int* idx = (const int*)d_in[3];
  const float* u = (const float*)d_in[4];
  float* out = (float*)d_out;

  double* thr = (double*)d_ws;                                        // 16384 f64
  double* I0 = (double*)((char*)d_ws + STEPS * sizeof(double));       // 4096 f64
  int* samemask = (int*)((char*)d_ws + STEPS * sizeof(double)
                                     + N * sizeof(double));           // 16384 i32

  pre_kernel<<<dim3(STEPS / 256), dim3(256), 0, stream>>>(u, idx, thr, samemask);
  init_field_kernel<<<dim3(N), dim3(256), 0, stream>>>(J, h, m0, I0);
  pbit_kernel<<<dim3(1), dim3(MBLK), 0, stream>>>(J, m0, idx, thr, samemask, I0, out);
}

// Round 7
// 1621.980 us; speedup vs baseline: 3.2575x; 3.2575x over previous
//
#include <hip/hip_runtime.h>
#include <math.h>

#define N 4096
#define STEPS 16384
#define WIN 32                 // steps resolved per barrier pair
#define NWIN (STEPS / WIN)
#define MBLK 1024
#define SBS 36   // padded stride (floats) for the 32x32 coupling block (float4-aligned)

// Workgroup barrier that does NOT drain vmcnt (LDS-only ordering between phases).
__device__ __forceinline__ void lgkm_barrier() {
  asm volatile("s_waitcnt lgkmcnt(0)\n\ts_barrier" ::: "memory");
}

// ---- prep: thr[t] = atanh(2u-1) in fp64; samemask[t] = window bits with same idx ----
__global__ __launch_bounds__(256) void pre_kernel(const float* __restrict__ u,
                                                  const int* __restrict__ idx,
                                                  double* __restrict__ thr,
                                                  int* __restrict__ samemask) {
  int t = blockIdx.x * 256 + threadIdx.x;
  if (t < STEPS) {
    float r = 2.0f * u[t] - 1.0f;          // exact same fp32 rounding as reference
    double rd = (double)r;
    thr[t] = 0.5 * log((1.0 + rd) / (1.0 - rd));   // r=-1 -> -inf (tie->+1 matches ref)
    int cbase = t & ~(WIN - 1);
    int my = idx[t];
    unsigned int sm = 0u;
    for (int q = 0; q < WIN; ++q)
      if (idx[cbase + q] == my) sm |= (1u << q);   // includes self bit
    samemask[t] = (int)sm;
  }
}

// ---- initial field: I0[row] = sum_k J[row,k]*m0[k] + h[row], fp64 accumulate ----
__global__ __launch_bounds__(256) void init_field_kernel(const float* __restrict__ J,
                                                         const float* __restrict__ h,
                                                         const float* __restrict__ m0,
                                                         double* __restrict__ I) {
  __shared__ double red[256];
  int row = blockIdx.x;
  const float4* Jr = (const float4*)(J + (size_t)row * N);
  const float4* mv = (const float4*)m0;
  double acc = 0.0;
  for (int q = threadIdx.x; q < N / 4; q += 256) {
    float4 a = Jr[q];
    float4 b = mv[q];
    acc += (double)(a.x * b.x) + (double)(a.y * b.y) +
           (double)(a.z * b.z) + (double)(a.w * b.w);
  }
  red[threadIdx.x] = acc;
  __syncthreads();
  for (int s = 128; s > 0; s >>= 1) {
    if (threadIdx.x < s) red[threadIdx.x] += red[threadIdx.x + s];
    __syncthreads();
  }
  if (threadIdx.x == 0) I[row] = red[0] + (double)h[row];
}

// ---- window-resolved Glauber chain: 1 workgroup, 1024 threads, WIN=32 ----
// Round-3 proven structure, resolve chain slimmed:
//  - flip lane f's delta/sign come from the D=ballot(sup) bit: dl_f = 2*s_f,
//    s_f = (D>>f)&1 ? +1 : -1   (no readlanes)
//  - duplicate-index spin update via samemask bit f (no readlane of idx)
//  - coupling Scol[f] = ST[f][t32] via ONE conflict-free ds_read_b32 per round
//    (replaces two uniform switch cascades AND the 8x ds_read_b128 fragment
//    preload at P1 entry)
// P1: wave0 resolves 32 steps flip-driven; workers park at the barrier.
// P2: all 1024 threads apply the F flipped rows; barriers are lgkm-only.
__global__ __launch_bounds__(MBLK) void pbit_kernel(const float* __restrict__ J,
                                                    const float* __restrict__ m0,
                                                    const int* __restrict__ idx,
                                                    const double* __restrict__ thr,
                                                    const int* __restrict__ samemask,
                                                    const double* __restrict__ I0,
                                                    float* __restrict__ out) {
  __shared__ __align__(16) double field_lds[N];        // 32 KB master field
  __shared__ __align__(16) float m_lds[N];             // 16 KB spins
  __shared__ __align__(16) float ST_lds[WIN * SBS];    // ST[r*SBS+c] = J[idx[r]][idx[c]] (sym)
  __shared__ __align__(16) int   pubi_lds[WIN];        // compacted flip rows
  __shared__ __align__(16) float pubd_lds[WIN];        // compacted deltas (+/-2)
  __shared__ int pubF_lds;                             // flip count

  const int tid = threadIdx.x;

  // owned field elements 4*tid..4*tid+3: fp64 registers + LDS write-through
  double i0, i1, i2, i3;
  {
    const double* ip = I0 + 4 * tid;
    i0 = ip[0]; i1 = ip[1]; i2 = ip[2]; i3 = ip[3];
    *(double2*)(field_lds + 4 * tid + 0) = make_double2(i0, i1);
    *(double2*)(field_lds + 4 * tid + 2) = make_double2(i2, i3);
  }
  ((float4*)m_lds)[tid] = ((const float4*)m0)[tid];

  const int t32 = tid & 31;      // step slot within window (lanes 32-63 duplicate)
  const int jrow = tid >> 1;     // gather row slot (wave0: 0..31)
  const int half = (tid & 1) * 16;  // gather col half

  // wave0 step-data pipeline (2 windows deep)
  int mi = 0, ni = 0;
  unsigned int msm = 0u, nsm = 0u;
  double mt = 0.0, nt = 0.0;

  if (tid < 64) {
    mi = idx[t32];       mt = thr[t32];       msm = (unsigned int)samemask[t32];
    ni = idx[WIN + t32]; nt = thr[WIN + t32]; nsm = (unsigned int)samemask[WIN + t32];
    // synchronous 32x32 block gather for window 0 (addrs via shfl from mi)
    int r0 = __shfl(mi, jrow);
    const float* Jr = J + (size_t)r0 * N;
#pragma unroll
    for (int q = 0; q < 16; ++q) {
      int c = __shfl(mi, half + q);
      ST_lds[jrow * SBS + half + q] = Jr[c];
    }
  }
  __syncthreads();

  for (int k = 0; k < NWIN; ++k) {
    // ---------------- P1: wave0 resolves 32 steps ----------------
    if (tid < 64) {
      // issue block gather for window k+1 (addrs via shfl from ni; stored after resolve)
      int growv = __shfl(ni, jrow);
      const float* Jg = J + (size_t)growv * N;
      int gc0  = __shfl(ni, half + 0),  gc1  = __shfl(ni, half + 1);
      int gc2  = __shfl(ni, half + 2),  gc3  = __shfl(ni, half + 3);
      int gc4  = __shfl(ni, half + 4),  gc5  = __shfl(ni, half + 5);
      int gc6  = __shfl(ni, half + 6),  gc7  = __shfl(ni, half + 7);
      int gc8  = __shfl(ni, half + 8),  gc9  = __shfl(ni, half + 9);
      int gc10 = __shfl(ni, half + 10), gc11 = __shfl(ni, half + 11);
      int gc12 = __shfl(ni, half + 12), gc13 = __shfl(ni, half + 13);
      int gc14 = __shfl(ni, half + 14), gc15 = __shfl(ni, half + 15);
      float gv0  = Jg[gc0],  gv1  = Jg[gc1],  gv2  = Jg[gc2],  gv3  = Jg[gc3];
      float gv4  = Jg[gc4],  gv5  = Jg[gc5],  gv6  = Jg[gc6],  gv7  = Jg[gc7];
      float gv8  = Jg[gc8],  gv9  = Jg[gc9],  gv10 = Jg[gc10], gv11 = Jg[gc11];
      float gv12 = Jg[gc12], gv13 = Jg[gc13], gv14 = Jg[gc14], gv15 = Jg[gc15];
      // issue step-data loads for window k+2
      int b2 = (k + 2) * WIN; if (b2 >= STEPS) b2 = 0;   // clamp: unused on tail
      int n2i = idx[b2 + t32];
      double n2t = thr[b2 + t32];
      unsigned int n2sm = (unsigned int)samemask[b2 + t32];
      // ---- flip-driven resolve: slim chain, no readlane / no switch ----
      double Ival = field_lds[mi];
      float mcur = m_lds[mi];
      float finals = 0.0f, finald = 0.0f;
      int conf = -1;
      bool locked = false;
      while (true) {
        bool sup = (Ival >= mt);                 // I >= atanh(r) <=> tanh(I) >= r
        float s = sup ? 1.0f : -1.0f;
        float dl = s - mcur;
        unsigned int D = (unsigned int)__ballot(sup);   // lanes 32-63 mirror 0-31
        unsigned long long mask = __ballot(dl != 0.0f) & 0xFFFFFFFFull;
        mask &= (~0ull) << (conf + 1);
        if (mask == 0) {
          if (!locked) { finals = s; finald = 0.0f; }
          break;
        }
        int f = (int)__builtin_ctzll(mask);      // wave-uniform
        if (!locked && t32 <= f) { finals = s; finald = dl; locked = true; }
        // flip lane f: flipped => dl_f = 2*s_f; s_f from ballot bit
        float s_f  = ((D >> f) & 1u) ? 1.0f : -1.0f;
        float dl_f = 2.0f * s_f;
        // Scol[f] for my lane = ST[f][t32]: conflict-free ds_read, f uniform
        float xcol = ST_lds[f * SBS + t32];
        Ival += (double)(xcol * dl_f);            // exact product: dl in {-2,2}
        if ((msm >> f) & 1u) mcur = s_f;          // same-idx step (incl. self)
        conf = f;
      }
      // publish: compacted flip list + m updates (last occurrence wins)
      unsigned long long fm = __ballot((tid < WIN) && (finald != 0.0f));
      if (tid < WIN) {
        if (finald != 0.0f) {
          int pos = __popcll(fm & ((1ull << t32) - 1ull));
          pubi_lds[pos] = mi;
          pubd_lds[pos] = finald;
        }
        bool mlo = (msm & (0xFFFFFFFEu << t32)) == 0u;   // no later same-idx step
        if (mlo) m_lds[mi] = finals;
        if (tid == 0) pubF_lds = (int)__popcll(fm);
      }
      // store block for window k+1 (gather waited here, ~resolve-length slack)
      {
        float* dst = &ST_lds[jrow * SBS + half];
        *(float4*)(dst + 0)  = make_float4(gv0, gv1, gv2, gv3);
        *(float4*)(dst + 4)  = make_float4(gv4, gv5, gv6, gv7);
        *(float4*)(dst + 8)  = make_float4(gv8, gv9, gv10, gv11);
        *(float4*)(dst + 12) = make_float4(gv12, gv13, gv14, gv15);
      }
      // rotate step-data pipeline
      mi = ni;  mt = nt;  msm = nsm;
      ni = n2i; nt = n2t; nsm = n2sm;
    }
    lgkm_barrier();

    // ---------------- P2: all threads apply the F flipped rows ----------------
    {
      int F = pubF_lds;
      if (F > 0) {                         // uniform: skip flip-free windows
        const float* Jb = J + 4 * (size_t)tid;
#pragma unroll
        for (int b = 0; b < WIN; b += 8) {
          if (b < F) {                     // uniform
            int4 r1 = *(const int4*)(pubi_lds + b);
            int4 r2 = *(const int4*)(pubi_lds + b + 4);
            float4 d1 = *(const float4*)(pubd_lds + b);
            float4 d2 = *(const float4*)(pubd_lds + b + 4);
            int rr[8] = {r1.x, r1.y, r1.z, r1.w, r2.x, r2.y, r2.z, r2.w};
            float dd[8] = {d1.x, d1.y, d1.z, d1.w, d2.x, d2.y, d2.z, d2.w};
            float4 rv[8];
            // loads first (back-to-back issue, one latency exposure per batch)
#pragma unroll
            for (int t = 0; t < 8; ++t)
              if (b + t < F) rv[t] = *(const float4*)(Jb + (size_t)rr[t] * N);
            float a0 = 0.f, a1 = 0.f, a2 = 0.f, a3 = 0.f;
#pragma unroll
            for (int t = 0; t < 8; ++t)
              if (b + t < F) {
                a0 += rv[t].x * dd[t]; a1 += rv[t].y * dd[t];
                a2 += rv[t].z * dd[t]; a3 += rv[t].w * dd[t];
              }
            // batch-local exact fp32 partials -> fp64 master
            i0 += (double)a0; i1 += (double)a1;
            i2 += (double)a2; i3 += (double)a3;
          }
        }
        *(double2*)(field_lds + 4 * tid + 0) = make_double2(i0, i1);
        *(double2*)(field_lds + 4 * tid + 2) = make_double2(i2, i3);
      }
    }
    lgkm_barrier();
  }

  __syncthreads();
  ((float4*)out)[tid] = ((const float4*)m_lds)[tid];
}

extern "C" void kernel_launch(void* const* d_in, const int* in_sizes, int n_in,
                              void* d_out, int out_size, void* d_ws, size_t ws_size,
                              hipStream_t stream) {
  const float* J = (const float*)d_in[0];
  const float* h = (const float*)d_in[1];
  const float* m0 = (const float*)d_in[2];
  const int* idx = (const int*)d_in[3];
  const float* u = (const float*)d_in[4];
  float* out = (float*)d_out;

  double* thr = (double*)d_ws;                                        // 16384 f64
  double* I0 = (double*)((char*)d_ws + STEPS * sizeof(double));       // 4096 f64
  int* samemask = (int*)((char*)d_ws + STEPS * sizeof(double)
                                     + N * sizeof(double));           // 16384 i32

  pre_kernel<<<dim3(STEPS / 256), dim3(256), 0, stream>>>(u, idx, thr, samemask);
  init_field_kernel<<<dim3(N), dim3(256), 0, stream>>>(J, h, m0, I0);
  pbit_kernel<<<dim3(1), dim3(MBLK), 0, stream>>>(J, m0, idx, thr, samemask, I0, out);
}